// Round 1
// baseline (835.885 us; speedup 1.0000x reference)
//
#include <hip/hip_runtime.h>
#include <math.h>

constexpr int NB = 2;       // B
constexpr int NS = 2048;    // S
constexpr int NM = 1024;    // D_MODEL (== K for all GEMMs)
constexpr int NH = 16;      // H
constexpr int ND = 64;      // D
constexpr int NDI = 1024;   // H*D

// ---------------- la[b,h,s] = -softplus(x[b,s,:]·Wa[:,h] + ba[h]) ----------------
__global__ __launch_bounds__(256) void k_alpha(const float* __restrict__ x,
    const float* __restrict__ Wa, const float* __restrict__ ba,
    float* __restrict__ la) {
  int bs = blockIdx.x;            // b*NS + s
  __shared__ float xs[NM];
  const float* xr = x + (size_t)bs * NM;
  for (int i = threadIdx.x; i < NM; i += 256) xs[i] = xr[i];
  __syncthreads();
  int h = threadIdx.x >> 4;
  int t = threadIdx.x & 15;
  float acc = 0.f;
  for (int i = t; i < NM; i += 16) acc += xs[i] * Wa[i * NH + h];
  acc += __shfl_xor(acc, 1, 64);
  acc += __shfl_xor(acc, 2, 64);
  acc += __shfl_xor(acc, 4, 64);
  acc += __shfl_xor(acc, 8, 64);
  if (t == 0) {
    float z = acc + ba[h];
    float sp = fmaxf(z, 0.f) + log1pf(expf(-fabsf(z)));   // stable softplus
    int b = bs / NS, s = bs % NS;
    la[((size_t)(b * NH + h)) * NS + s] = -sp;
  }
}

// ---------------- inclusive cumsum over s per (b,h) ----------------
__global__ __launch_bounds__(256) void k_cumsum(const float* __restrict__ la,
                                                float* __restrict__ cum) {
  int g = blockIdx.x;             // b*NH + h
  const float* in = la + (size_t)g * NS;
  float* out = cum + (size_t)g * NS;
  __shared__ float part[256];
  float v[8]; float sum = 0.f;
  int base = threadIdx.x * 8;
  #pragma unroll
  for (int i = 0; i < 8; i++) { v[i] = in[base + i]; sum += v[i]; }
  part[threadIdx.x] = sum;
  __syncthreads();
  for (int off = 1; off < 256; off <<= 1) {
    float add = (threadIdx.x >= off) ? part[threadIdx.x - off] : 0.f;
    __syncthreads();
    part[threadIdx.x] += add;
    __syncthreads();
  }
  float run = (threadIdx.x > 0) ? part[threadIdx.x - 1] : 0.f;
  #pragma unroll
  for (int i = 0; i < 8; i++) { run += v[i]; out[base + i] = run; }
}

// ---------------- fp32 tiled GEMM: C = act(A[ M x 1024 ] @ W[1024 x N]) ----------------
// 128x128 tile, 256 threads, 8x8 microtile. act: 0=none 1=silu 2=sigmoid
__device__ __forceinline__ void gemm_body(const float* __restrict__ A,
    const float* __restrict__ W, float* __restrict__ C, int N, int act,
    float (*As)[132], float (*Bs)[132]) {
  int tid = threadIdx.x;
  int row0 = blockIdx.y * 128, col0 = blockIdx.x * 128;
  int tx = tid & 15, ty = tid >> 4;
  int mrow = ty * 8, mcol = tx * 8;
  float acc[8][8];
  #pragma unroll
  for (int i = 0; i < 8; i++)
    #pragma unroll
    for (int j = 0; j < 8; j++) acc[i][j] = 0.f;
  for (int k0 = 0; k0 < NM; k0 += 16) {
    #pragma unroll
    for (int l = 0; l < 2; l++) {               // A tile 128x16 (stored transposed)
      int idx = tid + l * 256;                  // float4 idx 0..511
      int r = idx >> 2;
      int kk4 = (idx & 3) * 4;
      float4 a4 = *(const float4*)(A + (size_t)(row0 + r) * NM + k0 + kk4);
      As[kk4 + 0][r] = a4.x; As[kk4 + 1][r] = a4.y;
      As[kk4 + 2][r] = a4.z; As[kk4 + 3][r] = a4.w;
    }
    #pragma unroll
    for (int l = 0; l < 2; l++) {               // W tile 16x128
      int idx = tid + l * 256;
      int kk = idx >> 5;
      int c4 = (idx & 31) * 4;
      *(float4*)&Bs[kk][c4] = *(const float4*)(W + (size_t)(k0 + kk) * N + col0 + c4);
    }
    __syncthreads();
    #pragma unroll
    for (int kk = 0; kk < 16; kk++) {
      float4 a0 = *(const float4*)&As[kk][mrow];
      float4 a1 = *(const float4*)&As[kk][mrow + 4];
      float4 b0 = *(const float4*)&Bs[kk][mcol];
      float4 b1 = *(const float4*)&Bs[kk][mcol + 4];
      float a[8] = {a0.x,a0.y,a0.z,a0.w,a1.x,a1.y,a1.z,a1.w};
      float b[8] = {b0.x,b0.y,b0.z,b0.w,b1.x,b1.y,b1.z,b1.w};
      #pragma unroll
      for (int i = 0; i < 8; i++)
        #pragma unroll
        for (int j = 0; j < 8; j++)
          acc[i][j] = fmaf(a[i], b[j], acc[i][j]);
    }
    __syncthreads();
  }
  #pragma unroll
  for (int i = 0; i < 8; i++) {
    size_t rowoff = (size_t)(row0 + mrow + i) * N + col0 + mcol;
    #pragma unroll
    for (int j = 0; j < 8; j++) {
      float vv = acc[i][j];
      if (act == 1) vv = vv / (1.f + expf(-vv));        // silu
      else if (act == 2) vv = 1.f / (1.f + expf(-vv));  // sigmoid
      C[rowoff + j] = vv;
    }
  }
}

__global__ __launch_bounds__(256) void k_proj4(const float* __restrict__ A,
    const float* __restrict__ Wq, const float* __restrict__ Wk,
    const float* __restrict__ Wv, const float* __restrict__ Wg,
    float* __restrict__ q, float* __restrict__ k2, float* __restrict__ v2,
    float* __restrict__ g2) {
  __shared__ float As[16][132];
  __shared__ float Bs[16][132];
  int z = blockIdx.z;
  const float* W = (z == 0) ? Wq : (z == 1) ? Wk : (z == 2) ? Wv : Wg;
  float* C = (z == 0) ? q : (z == 1) ? k2 : (z == 2) ? v2 : g2;
  int act = (z < 2) ? 1 : (z == 2) ? 0 : 2;
  gemm_body(A, W, C, NDI, act, As, Bs);
}

__global__ __launch_bounds__(256) void k_gemm1(const float* __restrict__ A,
    const float* __restrict__ W, float* __restrict__ C, int N, int act) {
  __shared__ float As[16][132];
  __shared__ float Bs[16][132];
  gemm_body(A, W, C, N, act, As, Bs);
}

// ---------------- attention: per (b,h,i-tile of 64 rows) ----------------
// decay(i,j) = exp(cum_i - cum_j) <= 1 for j<=i; tiles with max exponent < -60 skipped.
__global__ __launch_bounds__(256) void k_attn(const float* __restrict__ q,
    const float* __restrict__ kk, const float* __restrict__ vv,
    const float* __restrict__ cum, float* __restrict__ o) {
  int it = blockIdx.x, h = blockIdx.y, b = blockIdx.z;
  int i0 = it * 64;
  __shared__ float Qs[64][65];
  __shared__ float Ks[64][65];   // reused for V
  __shared__ float Ps[64][65];   // decayed scores
  __shared__ float ci[64], cj[64];
  int tid = threadIdx.x;
  const size_t hb = (size_t)b * NS * NDI + (size_t)h * ND;  // (b, :, h, :)
  const float* cumh = cum + (size_t)(b * NH + h) * NS;
  #pragma unroll
  for (int l = 0; l < 4; l++) {
    int idx = tid + l * 256;
    int r = idx >> 4;
    int c4 = (idx & 15) * 4;
    float4 t4 = *(const float4*)(q + hb + (size_t)(i0 + r) * NDI + c4);
    Qs[r][c4] = t4.x; Qs[r][c4+1] = t4.y; Qs[r][c4+2] = t4.z; Qs[r][c4+3] = t4.w;
  }
  if (tid < 64) ci[tid] = cumh[i0 + tid];
  int tx = tid & 15, ty = tid >> 4;
  float acc[4][4];
  #pragma unroll
  for (int i = 0; i < 4; i++)
    #pragma unroll
    for (int j = 0; j < 4; j++) acc[i][j] = 0.f;
  for (int jt = 0; jt <= it; jt++) {
    int j0 = jt * 64;
    __syncthreads();                      // protects Ks/Ps/cj reuse + first-iter Qs/ci
    if (tid < 64) cj[tid] = cumh[j0 + tid];
    __syncthreads();
    if (ci[0] - cj[63] < -60.f) continue; // whole tile underflows (uniform branch)
    #pragma unroll
    for (int l = 0; l < 4; l++) {         // K tile
      int idx = tid + l * 256;
      int r = idx >> 4; int c4 = (idx & 15) * 4;
      float4 t4 = *(const float4*)(kk + hb + (size_t)(j0 + r) * NDI + c4);
      Ks[r][c4] = t4.x; Ks[r][c4+1] = t4.y; Ks[r][c4+2] = t4.z; Ks[r][c4+3] = t4.w;
    }
    __syncthreads();
    float s[4][4];
    #pragma unroll
    for (int i = 0; i < 4; i++)
      #pragma unroll
      for (int j = 0; j < 4; j++) s[i][j] = 0.f;
    for (int d = 0; d < ND; d++) {
      float a[4], bb2[4];
      #pragma unroll
      for (int i = 0; i < 4; i++) a[i] = Qs[ty*4+i][d];
      #pragma unroll
      for (int j = 0; j < 4; j++) bb2[j] = Ks[tx*4+j][d];
      #pragma unroll
      for (int i = 0; i < 4; i++)
        #pragma unroll
        for (int j = 0; j < 4; j++) s[i][j] = fmaf(a[i], bb2[j], s[i][j]);
    }
    #pragma unroll
    for (int i = 0; i < 4; i++) {
      float cii = ci[ty*4+i];
      int gi = i0 + ty*4 + i;
      #pragma unroll
      for (int j = 0; j < 4; j++) {
        int gj = j0 + tx*4 + j;
        float e = cii - cj[tx*4+j];
        float dec = (gj <= gi) ? expf(e) : 0.f;   // selection mask: no inf*0
        Ps[ty*4+i][tx*4+j] = s[i][j] * dec;
      }
    }
    __syncthreads();
    #pragma unroll
    for (int l = 0; l < 4; l++) {         // V tile over Ks
      int idx = tid + l * 256;
      int r = idx >> 4; int c4 = (idx & 15) * 4;
      float4 t4 = *(const float4*)(vv + hb + (size_t)(j0 + r) * NDI + c4);
      Ks[r][c4] = t4.x; Ks[r][c4+1] = t4.y; Ks[r][c4+2] = t4.z; Ks[r][c4+3] = t4.w;
    }
    __syncthreads();
    for (int jj = 0; jj < 64; jj++) {
      float sv[4], vr[4];
      #pragma unroll
      for (int i = 0; i < 4; i++) sv[i] = Ps[ty*4+i][jj];
      #pragma unroll
      for (int j = 0; j < 4; j++) vr[j] = Ks[jj][tx*4+j];
      #pragma unroll
      for (int i = 0; i < 4; i++)
        #pragma unroll
        for (int j = 0; j < 4; j++) acc[i][j] = fmaf(sv[i], vr[j], acc[i][j]);
    }
  }
  #pragma unroll
  for (int i = 0; i < 4; i++) {
    size_t ro = hb + (size_t)(i0 + ty*4 + i) * NDI;
    #pragma unroll
    for (int j = 0; j < 4; j++) o[ro + tx*4 + j] = acc[i][j];
  }
}

// ---------------- groupnorm stats: per (b,h) over (s,d) ----------------
__global__ __launch_bounds__(256) void k_gnpart(const float* __restrict__ o,
    float* __restrict__ psum, float* __restrict__ psq) {
  int chunk = blockIdx.x;   // 0..7
  int g = blockIdx.y;       // 0..31  (b*NH+h)
  int b = g >> 4, h = g & 15;
  int s0 = chunk * 256;
  int d = threadIdx.x & 63;
  int si = threadIdx.x >> 6;
  const size_t base = (size_t)b * NS * NDI + (size_t)h * ND + d;
  float sum = 0.f, sq = 0.f;
  for (int s = s0 + si; s < s0 + 256; s += 4) {
    float t = o[base + (size_t)s * NDI];
    sum += t; sq += t * t;
  }
  __shared__ float ls[256], lq[256];
  ls[threadIdx.x] = sum; lq[threadIdx.x] = sq;
  __syncthreads();
  for (int off = 128; off > 0; off >>= 1) {
    if (threadIdx.x < off) {
      ls[threadIdx.x] += ls[threadIdx.x + off];
      lq[threadIdx.x] += lq[threadIdx.x + off];
    }
    __syncthreads();
  }
  if (threadIdx.x == 0) { psum[g * 8 + chunk] = ls[0]; psq[g * 8 + chunk] = lq[0]; }
}

__global__ void k_gnfinal(const float* __restrict__ psum, const float* __restrict__ psq,
                          float* __restrict__ stats) {
  int g = threadIdx.x;
  if (g < 32) {
    float sum = 0.f, sq = 0.f;
    for (int c = 0; c < 8; c++) { sum += psum[g * 8 + c]; sq += psq[g * 8 + c]; }
    float n = (float)(NS * ND);
    float mean = sum / n;
    float var = sq / n - mean * mean;
    stats[g * 2] = mean;
    stats[g * 2 + 1] = rsqrtf(var + 1e-5f);
  }
}

// ---------------- u = groupnorm(o)*gn_w+gn_b, gated ----------------
__global__ __launch_bounds__(256) void k_gate(const float* __restrict__ o,
    const float* __restrict__ gsig, const float* __restrict__ stats,
    const float* __restrict__ gnw, const float* __restrict__ gnb,
    float* __restrict__ u) {
  int idx4 = blockIdx.x * 256 + threadIdx.x;   // float4 index; grid covers all
  size_t base = (size_t)idx4 * 4;
  int c = (int)(base & (NDI - 1));
  int row = (int)(base >> 10);
  int b = row >> 11;                           // row / NS
  int h = c >> 6;
  int g = b * NH + h;
  float mean = stats[g * 2], rstd = stats[g * 2 + 1];
  float4 ov = *(const float4*)(o + base);
  float4 gv = *(const float4*)(gsig + base);
  float4 w4 = *(const float4*)(gnw + c);
  float4 b4 = *(const float4*)(gnb + c);
  float4 r;
  r.x = ((ov.x - mean) * rstd * w4.x + b4.x) * gv.x;
  r.y = ((ov.y - mean) * rstd * w4.y + b4.y) * gv.y;
  r.z = ((ov.z - mean) * rstd * w4.z + b4.z) * gv.z;
  r.w = ((ov.w - mean) * rstd * w4.w + b4.w) * gv.w;
  *(float4*)(u + base) = r;
}

extern "C" void kernel_launch(void* const* d_in, const int* in_sizes, int n_in,
                              void* d_out, int out_size, void* d_ws, size_t ws_size,
                              hipStream_t stream) {
  const float* x   = (const float*)d_in[0];
  const float* Wq  = (const float*)d_in[1];
  const float* Wk  = (const float*)d_in[2];
  const float* Wv  = (const float*)d_in[3];
  const float* Wg  = (const float*)d_in[4];
  const float* Wa  = (const float*)d_in[5];
  const float* ba  = (const float*)d_in[6];
  const float* Wo  = (const float*)d_in[7];
  const float* gnw = (const float*)d_in[8];
  const float* gnb = (const float*)d_in[9];
  float* out = (float*)d_out;
  float* ws = (float*)d_ws;

  const size_t NTOK = (size_t)NB * NS;        // 4096
  float* la   = ws;                           // [B*H*S]
  float* cum  = la + (size_t)NB * NH * NS;    // [B*H*S]
  float* q    = cum + (size_t)NB * NH * NS;   // [4096][1024]
  float* k    = q + NTOK * NDI;
  float* v    = k + NTOK * NDI;
  float* g    = v + NTOK * NDI;               // sigmoid already applied
  float* o    = g + NTOK * NDI;
  float* u    = o + NTOK * NDI;
  float* psum = u + NTOK * NDI;               // [256]
  float* psq  = psum + 256;                   // [256]
  float* stats = psq + 256;                   // [64]
  // total ws: ~101.3 MB (fp32)

  k_alpha  <<<dim3(NB * NS), 256, 0, stream>>>(x, Wa, ba, la);
  k_cumsum <<<dim3(NB * NH), 256, 0, stream>>>(la, cum);
  k_proj4  <<<dim3(8, 32, 4), 256, 0, stream>>>(x, Wq, Wk, Wv, Wg, q, k, v, g);
  k_attn   <<<dim3(32, NH, NB), 256, 0, stream>>>(q, k, v, cum, o);
  k_gnpart <<<dim3(8, 32), 256, 0, stream>>>(o, psum, psq);
  k_gnfinal<<<1, 64, 0, stream>>>(psum, psq, stats);
  k_gate   <<<dim3(4096), 256, 0, stream>>>(o, g, stats, gnw, gnb, u);
  k_gemm1  <<<dim3(8, 32), 256, 0, stream>>>(u, Wo, out, NM, 0);
}

// Round 2
// 340.897 us; speedup vs baseline: 2.4520x; 2.4520x over previous
//
#include <hip/hip_runtime.h>
#include <math.h>
#include <stdint.h>

typedef __attribute__((ext_vector_type(4))) float f32x4;
typedef __attribute__((ext_vector_type(8))) short bf16x8;

constexpr int NB = 2;       // B
constexpr int NS = 2048;    // S
constexpr int NM = 1024;    // D_MODEL
constexpr int NH = 16;      // H
constexpr int ND = 64;      // D
constexpr int NDI = 1024;   // H*D

__device__ __forceinline__ float bf2f(unsigned short u) {
  uint32_t x = ((uint32_t)u) << 16; float f; __builtin_memcpy(&f, &x, 4); return f;
}
__device__ __forceinline__ unsigned short f2bf(float f) {
  uint32_t x; __builtin_memcpy(&x, &f, 4);
  x += 0x7FFFu + ((x >> 16) & 1u);            // RNE (finite values)
  return (unsigned short)(x >> 16);
}

// ---------------- x fp32 -> bf16 ----------------
__global__ __launch_bounds__(256) void k_cast_bf16(const float* __restrict__ in,
    unsigned short* __restrict__ out, int n8) {
  int i = blockIdx.x * 256 + threadIdx.x;
  if (i >= n8) return;
  const float4* p = (const float4*)(in + (size_t)i * 8);
  float4 a = p[0], b = p[1];
  unsigned short r[8] = {f2bf(a.x), f2bf(a.y), f2bf(a.z), f2bf(a.w),
                         f2bf(b.x), f2bf(b.y), f2bf(b.z), f2bf(b.w)};
  *(uint4*)(out + (size_t)i * 8) = *(const uint4*)r;
}

// ---------------- W fp32 [1024][1024] -> bf16 transposed [N][K] ----------------
__global__ __launch_bounds__(256) void k_castT5(
    const float* __restrict__ w0, const float* __restrict__ w1,
    const float* __restrict__ w2, const float* __restrict__ w3,
    const float* __restrict__ w4,
    unsigned short* __restrict__ t0, unsigned short* __restrict__ t1,
    unsigned short* __restrict__ t2, unsigned short* __restrict__ t3,
    unsigned short* __restrict__ t4) {
  __shared__ float tile[32][33];
  int z = blockIdx.z;
  const float* src = z == 0 ? w0 : z == 1 ? w1 : z == 2 ? w2 : z == 3 ? w3 : w4;
  unsigned short* dst = z == 0 ? t0 : z == 1 ? t1 : z == 2 ? t2 : z == 3 ? t3 : t4;
  int c0 = blockIdx.x * 32, r0 = blockIdx.y * 32;
  int tx = threadIdx.x & 31, ty = threadIdx.x >> 5;
  #pragma unroll
  for (int i = 0; i < 4; i++)
    tile[ty + i * 8][tx] = src[(size_t)(r0 + ty + i * 8) * 1024 + c0 + tx];
  __syncthreads();
  #pragma unroll
  for (int i = 0; i < 4; i++)
    dst[(size_t)(c0 + ty + i * 8) * 1024 + r0 + tx] = f2bf(tile[tx][ty + i * 8]);
}

// ---------------- la[b,h,s] = -softplus(x·Wa + ba) ----------------
__global__ __launch_bounds__(256) void k_alpha(const float* __restrict__ x,
    const float* __restrict__ Wa, const float* __restrict__ ba,
    float* __restrict__ la) {
  int bs = blockIdx.x;
  __shared__ float xs[NM];
  const float* xr = x + (size_t)bs * NM;
  for (int i = threadIdx.x; i < NM; i += 256) xs[i] = xr[i];
  __syncthreads();
  int h = threadIdx.x >> 4;
  int t = threadIdx.x & 15;
  float acc = 0.f;
  for (int i = t; i < NM; i += 16) acc += xs[i] * Wa[i * NH + h];
  acc += __shfl_xor(acc, 1, 64);
  acc += __shfl_xor(acc, 2, 64);
  acc += __shfl_xor(acc, 4, 64);
  acc += __shfl_xor(acc, 8, 64);
  if (t == 0) {
    float z = acc + ba[h];
    float sp = fmaxf(z, 0.f) + log1pf(expf(-fabsf(z)));
    int b = bs / NS, s = bs % NS;
    la[((size_t)(b * NH + h)) * NS + s] = -sp;
  }
}

// ---------------- inclusive cumsum over s per (b,h) ----------------
__global__ __launch_bounds__(256) void k_cumsum(const float* __restrict__ la,
                                                float* __restrict__ cum) {
  int g = blockIdx.x;
  const float* in = la + (size_t)g * NS;
  float* out = cum + (size_t)g * NS;
  __shared__ float part[256];
  float v[8]; float sum = 0.f;
  int base = threadIdx.x * 8;
  #pragma unroll
  for (int i = 0; i < 8; i++) { v[i] = in[base + i]; sum += v[i]; }
  part[threadIdx.x] = sum;
  __syncthreads();
  for (int off = 1; off < 256; off <<= 1) {
    float add = (threadIdx.x >= off) ? part[threadIdx.x - off] : 0.f;
    __syncthreads();
    part[threadIdx.x] += add;
    __syncthreads();
  }
  float run = (threadIdx.x > 0) ? part[threadIdx.x - 1] : 0.f;
  #pragma unroll
  for (int i = 0; i < 8; i++) { run += v[i]; out[base + i] = run; }
}

// ---------------- MFMA bf16 GEMM body (m97 structure) ----------------
// A bf16 [M][1024] row-major, Bt bf16 [N][1024] row-major (= W transposed).
// 128x128 tile, BK=32, 4 waves each computing 64x64 via 4x4 16x16x32 frags.
__device__ __forceinline__ void gemm_dev(const unsigned short* __restrict__ A,
    const unsigned short* __restrict__ Bt, void* __restrict__ Cp, int N,
    int act, int outbf) {
  __shared__ unsigned short As[128 * 32];
  __shared__ unsigned short Bs[128 * 32];
  int tid = threadIdx.x;
  int row0 = blockIdx.y * 128, col0 = blockIdx.x * 128;
  int w = tid >> 6, l = tid & 63;
  int wr = w >> 1, wc = w & 1;
  int lr = l & 15, lk = l >> 4;
  f32x4 acc[4][4] = {};
  for (int k0 = 0; k0 < NM; k0 += 32) {
    __syncthreads();                       // protect LDS reuse
    #pragma unroll
    for (int i = 0; i < 2; i++) {
      int idx = tid + i * 256;             // 16B-chunk index 0..511
      int r = idx >> 2, kb = (idx & 3) * 8;
      const unsigned short* srcA = A + (size_t)(row0 + r) * NM + k0 + kb;
      const unsigned short* srcB = Bt + (size_t)(col0 + r) * NM + k0 + kb;
      __builtin_amdgcn_global_load_lds(
          (const __attribute__((address_space(1))) void*)srcA,
          (__attribute__((address_space(3))) void*)((char*)As + (w * 64 + i * 256) * 16),
          16, 0, 0);
      __builtin_amdgcn_global_load_lds(
          (const __attribute__((address_space(1))) void*)srcB,
          (__attribute__((address_space(3))) void*)((char*)Bs + (w * 64 + i * 256) * 16),
          16, 0, 0);
    }
    __syncthreads();                       // vmcnt(0) drain + barrier
    bf16x8 a[4], b[4];
    #pragma unroll
    for (int m = 0; m < 4; m++)
      a[m] = *(const bf16x8*)&As[(wr * 64 + m * 16 + lr) * 32 + lk * 8];
    #pragma unroll
    for (int n = 0; n < 4; n++)
      b[n] = *(const bf16x8*)&Bs[(wc * 64 + n * 16 + lr) * 32 + lk * 8];
    #pragma unroll
    for (int m = 0; m < 4; m++)
      #pragma unroll
      for (int n = 0; n < 4; n++)
        acc[m][n] = __builtin_amdgcn_mfma_f32_16x16x32_bf16(a[m], b[n], acc[m][n], 0, 0, 0);
  }
  // epilogue: C/D layout col=lane&15, row=(lane>>4)*4+j (m89-verified)
  #pragma unroll
  for (int m = 0; m < 4; m++) {
    #pragma unroll
    for (int n = 0; n < 4; n++) {
      #pragma unroll
      for (int j = 0; j < 4; j++) {
        int row = row0 + wr * 64 + m * 16 + lk * 4 + j;
        int col = col0 + wc * 64 + n * 16 + lr;
        float v = acc[m][n][j];
        if (act == 1) v = v / (1.f + expf(-v));        // silu
        else if (act == 2) v = 1.f / (1.f + expf(-v)); // sigmoid
        if (outbf) ((unsigned short*)Cp)[(size_t)row * N + col] = f2bf(v);
        else       ((float*)Cp)[(size_t)row * N + col] = v;
      }
    }
  }
}

__global__ __launch_bounds__(256) void k_proj4m(const unsigned short* __restrict__ xb,
    const unsigned short* __restrict__ wtq, const unsigned short* __restrict__ wtk,
    const unsigned short* __restrict__ wtv, const unsigned short* __restrict__ wtg,
    unsigned short* __restrict__ q, unsigned short* __restrict__ k,
    unsigned short* __restrict__ v, unsigned short* __restrict__ g) {
  int z = blockIdx.z;
  const unsigned short* Bt = z == 0 ? wtq : z == 1 ? wtk : z == 2 ? wtv : wtg;
  unsigned short* C = z == 0 ? q : z == 1 ? k : z == 2 ? v : g;
  int act = (z < 2) ? 1 : (z == 2) ? 0 : 2;
  gemm_dev(xb, Bt, C, NDI, act, 1);
}

__global__ __launch_bounds__(256) void k_out_gemm(const unsigned short* __restrict__ u,
    const unsigned short* __restrict__ wto, float* __restrict__ out) {
  gemm_dev(u, wto, out, NM, 0, 0);
}

// ---------------- attention (bf16 in, fp32 compute, fp32 out) ----------------
__global__ __launch_bounds__(256) void k_attn(const unsigned short* __restrict__ q,
    const unsigned short* __restrict__ kk, const unsigned short* __restrict__ vv,
    const float* __restrict__ cum, float* __restrict__ o) {
  int it = blockIdx.x, h = blockIdx.y, b = blockIdx.z;
  int i0 = it * 64;
  __shared__ float Qs[64][65];
  __shared__ float Ks[64][65];   // reused for V
  __shared__ float Ps[64][65];
  __shared__ float ci[64], cj[64];
  int tid = threadIdx.x;
  const size_t hb = (size_t)b * NS * NDI + (size_t)h * ND;
  const float* cumh = cum + (size_t)(b * NH + h) * NS;
  #pragma unroll
  for (int lp = 0; lp < 2; lp++) {
    int idx = tid + lp * 256;           // 0..511, 8 bf16 each
    int r = idx >> 3, c8 = (idx & 7) * 8;
    uint4 t = *(const uint4*)(q + hb + (size_t)(i0 + r) * NDI + c8);
    unsigned short us[8]; *(uint4*)us = t;
    #pragma unroll
    for (int e = 0; e < 8; e++) Qs[r][c8 + e] = bf2f(us[e]);
  }
  if (tid < 64) ci[tid] = cumh[i0 + tid];
  int tx = tid & 15, ty = tid >> 4;
  float acc[4][4];
  #pragma unroll
  for (int i = 0; i < 4; i++)
    #pragma unroll
    for (int j = 0; j < 4; j++) acc[i][j] = 0.f;
  for (int jt = 0; jt <= it; jt++) {
    int j0 = jt * 64;
    __syncthreads();
    if (tid < 64) cj[tid] = cumh[j0 + tid];
    __syncthreads();
    if (ci[0] - cj[63] < -60.f) continue;   // tile fully underflows
    #pragma unroll
    for (int lp = 0; lp < 2; lp++) {
      int idx = tid + lp * 256;
      int r = idx >> 3, c8 = (idx & 7) * 8;
      uint4 t = *(const uint4*)(kk + hb + (size_t)(j0 + r) * NDI + c8);
      unsigned short us[8]; *(uint4*)us = t;
      #pragma unroll
      for (int e = 0; e < 8; e++) Ks[r][c8 + e] = bf2f(us[e]);
    }
    __syncthreads();
    float s[4][4];
    #pragma unroll
    for (int i = 0; i < 4; i++)
      #pragma unroll
      for (int j = 0; j < 4; j++) s[i][j] = 0.f;
    for (int d = 0; d < ND; d++) {
      float a[4], bb2[4];
      #pragma unroll
      for (int i = 0; i < 4; i++) a[i] = Qs[ty * 4 + i][d];
      #pragma unroll
      for (int j = 0; j < 4; j++) bb2[j] = Ks[tx * 4 + j][d];
      #pragma unroll
      for (int i = 0; i < 4; i++)
        #pragma unroll
        for (int j = 0; j < 4; j++) s[i][j] = fmaf(a[i], bb2[j], s[i][j]);
    }
    #pragma unroll
    for (int i = 0; i < 4; i++) {
      float cii = ci[ty * 4 + i];
      int gi = i0 + ty * 4 + i;
      #pragma unroll
      for (int j = 0; j < 4; j++) {
        int gj = j0 + tx * 4 + j;
        float e = cii - cj[tx * 4 + j];
        float dec = (gj <= gi) ? expf(e) : 0.f;
        Ps[ty * 4 + i][tx * 4 + j] = s[i][j] * dec;
      }
    }
    __syncthreads();
    #pragma unroll
    for (int lp = 0; lp < 2; lp++) {
      int idx = tid + lp * 256;
      int r = idx >> 3, c8 = (idx & 7) * 8;
      uint4 t = *(const uint4*)(vv + hb + (size_t)(j0 + r) * NDI + c8);
      unsigned short us[8]; *(uint4*)us = t;
      #pragma unroll
      for (int e = 0; e < 8; e++) Ks[r][c8 + e] = bf2f(us[e]);
    }
    __syncthreads();
    for (int jj = 0; jj < 64; jj++) {
      float sv[4], vr[4];
      #pragma unroll
      for (int i = 0; i < 4; i++) sv[i] = Ps[ty * 4 + i][jj];
      #pragma unroll
      for (int j = 0; j < 4; j++) vr[j] = Ks[jj][tx * 4 + j];
      #pragma unroll
      for (int i = 0; i < 4; i++)
        #pragma unroll
        for (int j = 0; j < 4; j++) acc[i][j] = fmaf(sv[i], vr[j], acc[i][j]);
    }
  }
  #pragma unroll
  for (int i = 0; i < 4; i++) {
    size_t ro = hb + (size_t)(i0 + ty * 4 + i) * NDI;
    #pragma unroll
    for (int j = 0; j < 4; j++) o[ro + tx * 4 + j] = acc[i][j];
  }
}

// ---------------- groupnorm stats ----------------
__global__ __launch_bounds__(256) void k_gnpart(const float* __restrict__ o,
    float* __restrict__ psum, float* __restrict__ psq) {
  int chunk = blockIdx.x;
  int g = blockIdx.y;
  int b = g >> 4, h = g & 15;
  int s0 = chunk * 256;
  int d = threadIdx.x & 63;
  int si = threadIdx.x >> 6;
  const size_t base = (size_t)b * NS * NDI + (size_t)h * ND + d;
  float sum = 0.f, sq = 0.f;
  for (int s = s0 + si; s < s0 + 256; s += 4) {
    float t = o[base + (size_t)s * NDI];
    sum += t; sq += t * t;
  }
  __shared__ float ls[256], lq[256];
  ls[threadIdx.x] = sum; lq[threadIdx.x] = sq;
  __syncthreads();
  for (int off = 128; off > 0; off >>= 1) {
    if (threadIdx.x < off) {
      ls[threadIdx.x] += ls[threadIdx.x + off];
      lq[threadIdx.x] += lq[threadIdx.x + off];
    }
    __syncthreads();
  }
  if (threadIdx.x == 0) { psum[g * 8 + chunk] = ls[0]; psq[g * 8 + chunk] = lq[0]; }
}

__global__ void k_gnfinal(const float* __restrict__ psum, const float* __restrict__ psq,
                          float* __restrict__ stats) {
  int g = threadIdx.x;
  if (g < 32) {
    float sum = 0.f, sq = 0.f;
    for (int c = 0; c < 8; c++) { sum += psum[g * 8 + c]; sq += psq[g * 8 + c]; }
    float n = (float)(NS * ND);
    float mean = sum / n;
    float var = sq / n - mean * mean;
    stats[g * 2] = mean;
    stats[g * 2 + 1] = rsqrtf(var + 1e-5f);
  }
}

// ---------------- u = (groupnorm(o)*w+b)*gate, bf16 out ----------------
__global__ __launch_bounds__(256) void k_gate(const float* __restrict__ o,
    const unsigned short* __restrict__ gsig, const float* __restrict__ stats,
    const float* __restrict__ gnw, const float* __restrict__ gnb,
    unsigned short* __restrict__ u) {
  int idx4 = blockIdx.x * 256 + threadIdx.x;
  size_t base = (size_t)idx4 * 4;
  int c = (int)(base & (NDI - 1));
  int row = (int)(base >> 10);
  int b = row >> 11;
  int h = c >> 6;
  int g = b * NH + h;
  float mean = stats[g * 2], rstd = stats[g * 2 + 1];
  float4 ov = *(const float4*)(o + base);
  ushort4 gv = *(const ushort4*)(gsig + base);
  float4 w4 = *(const float4*)(gnw + c);
  float4 b4 = *(const float4*)(gnb + c);
  unsigned short r[4];
  r[0] = f2bf(((ov.x - mean) * rstd * w4.x + b4.x) * bf2f(gv.x));
  r[1] = f2bf(((ov.y - mean) * rstd * w4.y + b4.y) * bf2f(gv.y));
  r[2] = f2bf(((ov.z - mean) * rstd * w4.z + b4.z) * bf2f(gv.z));
  r[3] = f2bf(((ov.w - mean) * rstd * w4.w + b4.w) * bf2f(gv.w));
  *(ushort4*)(u + base) = *(const ushort4*)r;
}

extern "C" void kernel_launch(void* const* d_in, const int* in_sizes, int n_in,
                              void* d_out, int out_size, void* d_ws, size_t ws_size,
                              hipStream_t stream) {
  const float* x   = (const float*)d_in[0];
  const float* Wq  = (const float*)d_in[1];
  const float* Wk  = (const float*)d_in[2];
  const float* Wv  = (const float*)d_in[3];
  const float* Wg  = (const float*)d_in[4];
  const float* Wa  = (const float*)d_in[5];
  const float* ba  = (const float*)d_in[6];
  const float* Wo  = (const float*)d_in[7];
  const float* gnw = (const float*)d_in[8];
  const float* gnb = (const float*)d_in[9];
  float* out = (float*)d_out;

  const size_t NTOK = (size_t)NB * NS;        // 4096
  char* p = (char*)d_ws;
  float* la  = (float*)p;                 p += (size_t)NB * NH * NS * 4;
  float* cum = (float*)p;                 p += (size_t)NB * NH * NS * 4;
  float* psum = (float*)p;                p += 256 * 4;
  float* psq  = (float*)p;                p += 256 * 4;
  float* stats = (float*)p;               p += 64 * 4;
  p = (char*)(((uintptr_t)p + 255) & ~(uintptr_t)255);
  unsigned short* xb  = (unsigned short*)p; p += NTOK * NM * 2;        // 8 MB
  unsigned short* wtq = (unsigned short*)p; p += (size_t)NM * NDI * 2; // 2 MB
  unsigned short* wtk = (unsigned short*)p; p += (size_t)NM * NDI * 2;
  unsigned short* wtv = (unsigned short*)p; p += (size_t)NM * NDI * 2;
  unsigned short* wtg = (unsigned short*)p; p += (size_t)NM * NDI * 2;
  unsigned short* wto = (unsigned short*)p; p += (size_t)NDI * NM * 2;
  unsigned short* q  = (unsigned short*)p;  p += NTOK * NDI * 2;       // 8 MB
  unsigned short* k  = (unsigned short*)p;  p += NTOK * NDI * 2;
  unsigned short* v  = (unsigned short*)p;  p += NTOK * NDI * 2;
  unsigned short* g  = (unsigned short*)p;  p += NTOK * NDI * 2;
  unsigned short* u  = (unsigned short*)p;  p += NTOK * NDI * 2;
  float* o = (float*)p;                     p += NTOK * NDI * 4;       // 16 MB
  // total ~75 MB

  k_cast_bf16<<<dim3((int)(NTOK * NM / 8 / 256)), 256, 0, stream>>>(x, xb, (int)(NTOK * NM / 8));
  k_castT5   <<<dim3(32, 32, 5), 256, 0, stream>>>(Wq, Wk, Wv, Wg, Wo, wtq, wtk, wtv, wtg, wto);
  k_alpha    <<<dim3(NB * NS), 256, 0, stream>>>(x, Wa, ba, la);
  k_cumsum   <<<dim3(NB * NH), 256, 0, stream>>>(la, cum);
  k_proj4m   <<<dim3(8, 32, 4), 256, 0, stream>>>(xb, wtq, wtk, wtv, wtg, q, k, v, g);
  k_attn     <<<dim3(32, NH, NB), 256, 0, stream>>>(q, k, v, cum, o);
  k_gnpart   <<<dim3(8, 32), 256, 0, stream>>>(o, psum, psq);
  k_gnfinal  <<<1, 64, 0, stream>>>(psum, psq, stats);
  k_gate     <<<dim3(4096), 256, 0, stream>>>(o, g, stats, gnw, gnb, u);
  k_out_gemm <<<dim3(8, 32), 256, 0, stream>>>(u, wto, out);
}

// Round 3
// 189.438 us; speedup vs baseline: 4.4124x; 1.7995x over previous
//
#include <hip/hip_runtime.h>
#include <math.h>
#include <stdint.h>

typedef __attribute__((ext_vector_type(4))) float f32x4;
typedef __attribute__((ext_vector_type(8))) short bf16x8;

constexpr int NB = 2;       // B
constexpr int NS = 2048;    // S
constexpr int NM = 1024;    // D_MODEL
constexpr int NH = 16;      // H
constexpr int ND = 64;      // D
constexpr int NDI = 1024;   // H*D

__device__ __forceinline__ float bf2f(unsigned short u) {
  uint32_t x = ((uint32_t)u) << 16; float f; __builtin_memcpy(&f, &x, 4); return f;
}
__device__ __forceinline__ unsigned short f2bf(float f) {
  uint32_t x; __builtin_memcpy(&x, &f, 4);
  x += 0x7FFFu + ((x >> 16) & 1u);            // RNE (finite values)
  return (unsigned short)(x >> 16);
}

// ---------------- x fp32 -> bf16 ----------------
__global__ __launch_bounds__(256) void k_cast_bf16(const float* __restrict__ in,
    unsigned short* __restrict__ out, int n8) {
  int i = blockIdx.x * 256 + threadIdx.x;
  if (i >= n8) return;
  const float4* p = (const float4*)(in + (size_t)i * 8);
  float4 a = p[0], b = p[1];
  unsigned short r[8] = {f2bf(a.x), f2bf(a.y), f2bf(a.z), f2bf(a.w),
                         f2bf(b.x), f2bf(b.y), f2bf(b.z), f2bf(b.w)};
  *(uint4*)(out + (size_t)i * 8) = *(const uint4*)r;
}

// ---------------- W fp32 [1024][1024] -> bf16 transposed [N][K] ----------------
__global__ __launch_bounds__(256) void k_castT5(
    const float* __restrict__ w0, const float* __restrict__ w1,
    const float* __restrict__ w2, const float* __restrict__ w3,
    const float* __restrict__ w4,
    unsigned short* __restrict__ t0, unsigned short* __restrict__ t1,
    unsigned short* __restrict__ t2, unsigned short* __restrict__ t3,
    unsigned short* __restrict__ t4) {
  __shared__ float tile[32][33];
  int z = blockIdx.z;
  const float* src = z == 0 ? w0 : z == 1 ? w1 : z == 2 ? w2 : z == 3 ? w3 : w4;
  unsigned short* dst = z == 0 ? t0 : z == 1 ? t1 : z == 2 ? t2 : z == 3 ? t3 : t4;
  int c0 = blockIdx.x * 32, r0 = blockIdx.y * 32;
  int tx = threadIdx.x & 31, ty = threadIdx.x >> 5;
  #pragma unroll
  for (int i = 0; i < 4; i++)
    tile[ty + i * 8][tx] = src[(size_t)(r0 + ty + i * 8) * 1024 + c0 + tx];
  __syncthreads();
  #pragma unroll
  for (int i = 0; i < 4; i++)
    dst[(size_t)(c0 + ty + i * 8) * 1024 + r0 + tx] = f2bf(tile[tx][ty + i * 8]);
}

// ---------------- Wa fp32 [1024][16] -> bf16 padded-transposed [128][1024] ----------------
__global__ __launch_bounds__(256) void k_wa_fill(const float* __restrict__ Wa,
    unsigned short* __restrict__ wa_pad) {
  int idx = blockIdx.x * 256 + threadIdx.x;   // 0..131071
  int h = idx >> 10, k2 = idx & 1023;
  wa_pad[idx] = (h < 16) ? f2bf(Wa[k2 * 16 + h]) : (unsigned short)0;
}

// ---------------- inclusive cumsum over s per (b,h) ----------------
__global__ __launch_bounds__(256) void k_cumsum(const float* __restrict__ la,
                                                float* __restrict__ cum) {
  int g = blockIdx.x;
  const float* in = la + (size_t)g * NS;
  float* out = cum + (size_t)g * NS;
  __shared__ float part[256];
  float v[8]; float sum = 0.f;
  int base = threadIdx.x * 8;
  #pragma unroll
  for (int i = 0; i < 8; i++) { v[i] = in[base + i]; sum += v[i]; }
  part[threadIdx.x] = sum;
  __syncthreads();
  for (int off = 1; off < 256; off <<= 1) {
    float add = (threadIdx.x >= off) ? part[threadIdx.x - off] : 0.f;
    __syncthreads();
    part[threadIdx.x] += add;
    __syncthreads();
  }
  float run = (threadIdx.x > 0) ? part[threadIdx.x - 1] : 0.f;
  #pragma unroll
  for (int i = 0; i < 8; i++) { run += v[i]; out[base + i] = run; }
}

// ---------------- MFMA bf16 GEMM body (m97 structure) ----------------
// A bf16 [M][1024] row-major, Bt bf16 [N][1024] row-major.
// 128x128 tile, BK=32, 4 waves each 64x64 via 4x4 16x16x32 frags.
// act: 0 none, 1 silu, 2 sigmoid (outbf picks bf16/f32 store)
// act 3: la epilogue: la[(b*16+h)*2048+s] = -softplus(v + ba[h]) for cols<16
__device__ __forceinline__ void gemm_dev(const unsigned short* __restrict__ A,
    const unsigned short* __restrict__ Bt, void* __restrict__ Cp, int N,
    int act, int outbf, int by, int bx, const float* __restrict__ ba) {
  __shared__ unsigned short As[128 * 32];
  __shared__ unsigned short Bs[128 * 32];
  int tid = threadIdx.x;
  int row0 = by * 128, col0 = bx * 128;
  int w = tid >> 6, l = tid & 63;
  int wr = w >> 1, wc = w & 1;
  int lr = l & 15, lk = l >> 4;
  f32x4 acc[4][4] = {};
  for (int k0 = 0; k0 < NM; k0 += 32) {
    __syncthreads();
    #pragma unroll
    for (int i = 0; i < 2; i++) {
      int idx = tid + i * 256;             // 16B-chunk index 0..511
      int r = idx >> 2, kb = (idx & 3) * 8;
      const unsigned short* srcA = A + (size_t)(row0 + r) * NM + k0 + kb;
      const unsigned short* srcB = Bt + (size_t)(col0 + r) * NM + k0 + kb;
      __builtin_amdgcn_global_load_lds(
          (const __attribute__((address_space(1))) void*)srcA,
          (__attribute__((address_space(3))) void*)((char*)As + (w * 64 + i * 256) * 16),
          16, 0, 0);
      __builtin_amdgcn_global_load_lds(
          (const __attribute__((address_space(1))) void*)srcB,
          (__attribute__((address_space(3))) void*)((char*)Bs + (w * 64 + i * 256) * 16),
          16, 0, 0);
    }
    __syncthreads();
    bf16x8 a[4], b[4];
    #pragma unroll
    for (int m = 0; m < 4; m++)
      a[m] = *(const bf16x8*)&As[(wr * 64 + m * 16 + lr) * 32 + lk * 8];
    #pragma unroll
    for (int n = 0; n < 4; n++)
      b[n] = *(const bf16x8*)&Bs[(wc * 64 + n * 16 + lr) * 32 + lk * 8];
    #pragma unroll
    for (int m = 0; m < 4; m++)
      #pragma unroll
      for (int n = 0; n < 4; n++)
        acc[m][n] = __builtin_amdgcn_mfma_f32_16x16x32_bf16(a[m], b[n], acc[m][n], 0, 0, 0);
  }
  if (act == 3) {                          // alpha-logit epilogue
    if (wc == 0) {
      float bah = ba[lr];
      #pragma unroll
      for (int m = 0; m < 4; m++) {
        #pragma unroll
        for (int j = 0; j < 4; j++) {
          int row = row0 + wr * 64 + m * 16 + lk * 4 + j;   // token index
          float z = acc[m][0][j] + bah;
          float sp = fmaxf(z, 0.f) + log1pf(expf(-fabsf(z)));
          int bb = row >> 11, s = row & 2047;
          ((float*)Cp)[((size_t)(bb * 16 + lr)) * 2048 + s] = -sp;
        }
      }
    }
    return;
  }
  #pragma unroll
  for (int m = 0; m < 4; m++) {
    #pragma unroll
    for (int n = 0; n < 4; n++) {
      #pragma unroll
      for (int j = 0; j < 4; j++) {
        int row = row0 + wr * 64 + m * 16 + lk * 4 + j;
        int col = col0 + wc * 64 + n * 16 + lr;
        float v = acc[m][n][j];
        if (act == 1) v = v / (1.f + expf(-v));
        else if (act == 2) v = 1.f / (1.f + expf(-v));
        if (outbf) ((unsigned short*)Cp)[(size_t)row * N + col] = f2bf(v);
        else       ((float*)Cp)[(size_t)row * N + col] = v;
      }
    }
  }
}

__global__ __launch_bounds__(256) void k_proj4m(const unsigned short* __restrict__ xb,
    const unsigned short* __restrict__ wtq, const unsigned short* __restrict__ wtk,
    const unsigned short* __restrict__ wtv, const unsigned short* __restrict__ wtg,
    const unsigned short* __restrict__ wa_pad, const float* __restrict__ ba,
    unsigned short* __restrict__ q, unsigned short* __restrict__ k,
    unsigned short* __restrict__ v, unsigned short* __restrict__ g,
    float* __restrict__ la) {
  int z = blockIdx.z;
  bool isla = (blockIdx.x == 8);
  if (isla && z != 0) return;
  const unsigned short* Bt = isla ? wa_pad : (z == 0 ? wtq : z == 1 ? wtk : z == 2 ? wtv : wtg);
  void* C = isla ? (void*)la : (z == 0 ? (void*)q : z == 1 ? (void*)k : z == 2 ? (void*)v : (void*)g);
  int act = isla ? 3 : ((z < 2) ? 1 : (z == 2) ? 0 : 2);
  int bx = isla ? 0 : blockIdx.x;
  gemm_dev(xb, Bt, C, NDI, act, 1, blockIdx.y, bx, ba);
}

__global__ __launch_bounds__(256) void k_out_gemm(const unsigned short* __restrict__ u,
    const unsigned short* __restrict__ wto, float* __restrict__ out) {
  gemm_dev(u, wto, out, NM, 0, 0, blockIdx.y, blockIdx.x, nullptr);
}

// ---------------- MFMA attention: per (b,h,i-tile of 64 rows) ----------------
// S = Q K^T (bf16 MFMA, fp32 acc); P = S*exp(ci-cj) -> bf16; O += P V (MFMA).
// Q/K/P in XOR-swizzled LDS (byte ^= (row&7)<<4) for conflict-free b128.
// V row-major padded to 66 halfwords (column u16 reads bank-spread).
__global__ __launch_bounds__(256) void k_attn(const unsigned short* __restrict__ q,
    const unsigned short* __restrict__ kk, const unsigned short* __restrict__ vv,
    const float* __restrict__ cum, float* __restrict__ o) {
  int it = blockIdx.x, h = blockIdx.y, b = blockIdx.z;
  int i0 = it * 64;
  __shared__ unsigned short Qs[64 * 64];
  __shared__ unsigned short Ks[64 * 64];
  __shared__ unsigned short Ps[64 * 64];
  __shared__ unsigned short Vs[64 * 66];
  __shared__ float ci[64], cj[64];
  int tid = threadIdx.x;
  int w = tid >> 6, lane = tid & 63;
  int cl = lane & 15, hi = lane >> 4;
  const size_t hb = (size_t)b * NS * NDI + (size_t)h * ND;
  const float* cumh = cum + (size_t)(b * NH + h) * NS;

  // stage Q (swizzled) + ci
  #pragma unroll
  for (int lp = 0; lp < 2; lp++) {
    int idx = tid + lp * 256;
    int r = idx >> 3, cb = (idx & 7) * 16;     // byte col offset
    uint4 t = *(const uint4*)(q + hb + (size_t)(i0 + r) * NDI + (cb >> 1));
    *(uint4*)((char*)Qs + r * 128 + (cb ^ ((r & 7) << 4))) = t;
  }
  if (tid < 64) ci[tid] = cumh[i0 + tid];

  int arow = w * 16 + cl;                      // this lane's A-fragment row
  int xr = (cl & 7) << 4;                      // swizzle term (arow&7 == cl&7)
  const char* Qb = (const char*)Qs + arow * 128;
  const char* Pb = (const char*)Ps + arow * 128;
  f32x4 acco[4] = {};

  for (int jt = 0; jt <= it; jt++) {
    int j0 = jt * 64;
    __syncthreads();                           // prior reads of Ks/Vs/Ps/cj done
    if (tid < 64) cj[tid] = cumh[j0 + tid];
    __syncthreads();
    if (ci[0] - cj[63] < -60.f) continue;      // tile fully underflows (uniform)
    #pragma unroll
    for (int lp = 0; lp < 2; lp++) {
      int idx = tid + lp * 256;
      int r = idx >> 3, cb = (idx & 7) * 16;
      uint4 t = *(const uint4*)(kk + hb + (size_t)(j0 + r) * NDI + (cb >> 1));
      *(uint4*)((char*)Ks + r * 128 + (cb ^ ((r & 7) << 4))) = t;
      uint4 tv = *(const uint4*)(vv + hb + (size_t)(j0 + r) * NDI + (cb >> 1));
      unsigned int uv[4]; *(uint4*)uv = tv;
      unsigned int* vd = (unsigned int*)(Vs + r * 66 + (cb >> 1));   // 4B-aligned
      vd[0] = uv[0]; vd[1] = uv[1]; vd[2] = uv[2]; vd[3] = uv[3];
    }
    __syncthreads();
    // ---- QK^T ----
    bf16x8 a0 = *(const bf16x8*)(Qb + ((hi * 16) ^ xr));
    bf16x8 a1 = *(const bf16x8*)(Qb + ((64 + hi * 16) ^ xr));
    f32x4 accs[4] = {};
    #pragma unroll
    for (int jtile = 0; jtile < 4; jtile++) {
      const char* Kb = (const char*)Ks + (jtile * 16 + cl) * 128;
      bf16x8 b0 = *(const bf16x8*)(Kb + ((hi * 16) ^ xr));
      bf16x8 b1 = *(const bf16x8*)(Kb + ((64 + hi * 16) ^ xr));
      accs[jtile] = __builtin_amdgcn_mfma_f32_16x16x32_bf16(a0, b0, accs[jtile], 0, 0, 0);
      accs[jtile] = __builtin_amdgcn_mfma_f32_16x16x32_bf16(a1, b1, accs[jtile], 0, 0, 0);
    }
    // ---- decay + P (bf16, swizzled) ----
    #pragma unroll
    for (int jtile = 0; jtile < 4; jtile++) {
      #pragma unroll
      for (int reg = 0; reg < 4; reg++) {
        int irl = w * 16 + hi * 4 + reg;
        int jl = jtile * 16 + cl;
        float dec = ((j0 + jl) <= (i0 + irl)) ? __expf(ci[irl] - cj[jl]) : 0.f;
        float pv = accs[jtile][reg] * dec;
        *(unsigned short*)((char*)Ps + irl * 128 + ((2 * jl) ^ ((irl & 7) << 4))) = f2bf(pv);
      }
    }
    // ---- PV (wave reads only its own 16 P-rows; same-wave LDS in-order) ----
    #pragma unroll
    for (int kk2 = 0; kk2 < 2; kk2++) {
      bf16x8 pa = *(const bf16x8*)(Pb + ((kk2 * 64 + hi * 16) ^ xr));
      #pragma unroll
      for (int dt = 0; dt < 4; dt++) {
        bf16x8 vb;
        #pragma unroll
        for (int e = 0; e < 8; e++)
          vb[e] = (short)Vs[(kk2 * 32 + hi * 8 + e) * 66 + dt * 16 + cl];
        acco[dt] = __builtin_amdgcn_mfma_f32_16x16x32_bf16(pa, vb, acco[dt], 0, 0, 0);
      }
    }
  }
  #pragma unroll
  for (int dt = 0; dt < 4; dt++) {
    #pragma unroll
    for (int reg = 0; reg < 4; reg++) {
      int row = i0 + w * 16 + hi * 4 + reg;
      o[hb + (size_t)row * NDI + dt * 16 + cl] = acco[dt][reg];
    }
  }
}

// ---------------- groupnorm stats ----------------
__global__ __launch_bounds__(256) void k_gnpart(const float* __restrict__ o,
    float* __restrict__ psum, float* __restrict__ psq) {
  int chunk = blockIdx.x;
  int g = blockIdx.y;
  int b = g >> 4, h = g & 15;
  int s0 = chunk * 256;
  int d = threadIdx.x & 63;
  int si = threadIdx.x >> 6;
  const size_t base = (size_t)b * NS * NDI + (size_t)h * ND + d;
  float sum = 0.f, sq = 0.f;
  for (int s = s0 + si; s < s0 + 256; s += 4) {
    float t = o[base + (size_t)s * NDI];
    sum += t; sq += t * t;
  }
  __shared__ float ls[256], lq[256];
  ls[threadIdx.x] = sum; lq[threadIdx.x] = sq;
  __syncthreads();
  for (int off = 128; off > 0; off >>= 1) {
    if (threadIdx.x < off) {
      ls[threadIdx.x] += ls[threadIdx.x + off];
      lq[threadIdx.x] += lq[threadIdx.x + off];
    }
    __syncthreads();
  }
  if (threadIdx.x == 0) { psum[g * 8 + chunk] = ls[0]; psq[g * 8 + chunk] = lq[0]; }
}

__global__ void k_gnfinal(const float* __restrict__ psum, const float* __restrict__ psq,
                          float* __restrict__ stats) {
  int g = threadIdx.x;
  if (g < 32) {
    float sum = 0.f, sq = 0.f;
    for (int c = 0; c < 8; c++) { sum += psum[g * 8 + c]; sq += psq[g * 8 + c]; }
    float n = (float)(NS * ND);
    float mean = sum / n;
    float var = sq / n - mean * mean;
    stats[g * 2] = mean;
    stats[g * 2 + 1] = rsqrtf(var + 1e-5f);
  }
}

// ---------------- u = (groupnorm(o)*w+b)*gate, bf16 out ----------------
__global__ __launch_bounds__(256) void k_gate(const float* __restrict__ o,
    const unsigned short* __restrict__ gsig, const float* __restrict__ stats,
    const float* __restrict__ gnw, const float* __restrict__ gnb,
    unsigned short* __restrict__ u) {
  int idx4 = blockIdx.x * 256 + threadIdx.x;
  size_t base = (size_t)idx4 * 4;
  int c = (int)(base & (NDI - 1));
  int row = (int)(base >> 10);
  int b = row >> 11;
  int h = c >> 6;
  int g = b * NH + h;
  float mean = stats[g * 2], rstd = stats[g * 2 + 1];
  float4 ov = *(const float4*)(o + base);
  ushort4 gv = *(const ushort4*)(gsig + base);
  float4 w4 = *(const float4*)(gnw + c);
  float4 b4 = *(const float4*)(gnb + c);
  unsigned short r[4];
  r[0] = f2bf(((ov.x - mean) * rstd * w4.x + b4.x) * bf2f(gv.x));
  r[1] = f2bf(((ov.y - mean) * rstd * w4.y + b4.y) * bf2f(gv.y));
  r[2] = f2bf(((ov.z - mean) * rstd * w4.z + b4.z) * bf2f(gv.z));
  r[3] = f2bf(((ov.w - mean) * rstd * w4.w + b4.w) * bf2f(gv.w));
  *(ushort4*)(u + base) = *(const ushort4*)r;
}

extern "C" void kernel_launch(void* const* d_in, const int* in_sizes, int n_in,
                              void* d_out, int out_size, void* d_ws, size_t ws_size,
                              hipStream_t stream) {
  const float* x   = (const float*)d_in[0];
  const float* Wq  = (const float*)d_in[1];
  const float* Wk  = (const float*)d_in[2];
  const float* Wv  = (const float*)d_in[3];
  const float* Wg  = (const float*)d_in[4];
  const float* Wa  = (const float*)d_in[5];
  const float* ba  = (const float*)d_in[6];
  const float* Wo  = (const float*)d_in[7];
  const float* gnw = (const float*)d_in[8];
  const float* gnb = (const float*)d_in[9];
  float* out = (float*)d_out;

  const size_t NTOK = (size_t)NB * NS;        // 4096
  char* p = (char*)d_ws;
  float* la  = (float*)p;                 p += (size_t)NB * NH * NS * 4;
  float* cum = (float*)p;                 p += (size_t)NB * NH * NS * 4;
  float* psum = (float*)p;                p += 256 * 4;
  float* psq  = (float*)p;                p += 256 * 4;
  float* stats = (float*)p;               p += 64 * 4;
  p = (char*)(((uintptr_t)p + 255) & ~(uintptr_t)255);
  unsigned short* xb  = (unsigned short*)p; p += NTOK * NM * 2;        // 8 MB
  unsigned short* wtq = (unsigned short*)p; p += (size_t)NM * NDI * 2; // 2 MB
  unsigned short* wtk = (unsigned short*)p; p += (size_t)NM * NDI * 2;
  unsigned short* wtv = (unsigned short*)p; p += (size_t)NM * NDI * 2;
  unsigned short* wtg = (unsigned short*)p; p += (size_t)NM * NDI * 2;
  unsigned short* wto = (unsigned short*)p; p += (size_t)NDI * NM * 2;
  unsigned short* wa_pad = (unsigned short*)p; p += (size_t)128 * NM * 2; // 256 KB
  unsigned short* q  = (unsigned short*)p;  p += NTOK * NDI * 2;       // 8 MB
  unsigned short* k  = (unsigned short*)p;  p += NTOK * NDI * 2;
  unsigned short* v  = (unsigned short*)p;  p += NTOK * NDI * 2;
  unsigned short* g  = (unsigned short*)p;  p += NTOK * NDI * 2;
  unsigned short* u  = (unsigned short*)p;  p += NTOK * NDI * 2;
  float* o = (float*)p;                     p += NTOK * NDI * 4;       // 16 MB

  k_cast_bf16<<<dim3((int)(NTOK * NM / 8 / 256)), 256, 0, stream>>>(x, xb, (int)(NTOK * NM / 8));
  k_castT5   <<<dim3(32, 32, 5), 256, 0, stream>>>(Wq, Wk, Wv, Wg, Wo, wtq, wtk, wtv, wtg, wto);
  k_wa_fill  <<<dim3(512), 256, 0, stream>>>(Wa, wa_pad);
  k_proj4m   <<<dim3(9, 32, 4), 256, 0, stream>>>(xb, wtq, wtk, wtv, wtg, wa_pad, ba,
                                                  q, k, v, g, la);
  k_cumsum   <<<dim3(NB * NH), 256, 0, stream>>>(la, cum);
  k_attn     <<<dim3(32, NH, NB), 256, 0, stream>>>(q, k, v, cum, o);
  k_gnpart   <<<dim3(8, 32), 256, 0, stream>>>(o, psum, psq);
  k_gnfinal  <<<1, 64, 0, stream>>>(psum, psq, stats);
  k_gate     <<<dim3(4096), 256, 0, stream>>>(o, g, stats, gnw, gnb, u);
  k_out_gemm <<<dim3(8, 32), 256, 0, stream>>>(u, wto, out);
}

// Round 4
// 168.085 us; speedup vs baseline: 4.9730x; 1.1270x over previous
//
#include <hip/hip_runtime.h>
#include <math.h>
#include <stdint.h>

typedef __attribute__((ext_vector_type(4))) float f32x4;
typedef __attribute__((ext_vector_type(8))) short bf16x8;

constexpr int NB = 2;       // B
constexpr int NS = 2048;    // S
constexpr int NM = 1024;    // D_MODEL
constexpr int NH = 16;      // H
constexpr int ND = 64;      // D
constexpr int NDI = 1024;   // H*D

__device__ __forceinline__ float bf2f(unsigned short u) {
  uint32_t x = ((uint32_t)u) << 16; float f; __builtin_memcpy(&f, &x, 4); return f;
}
__device__ __forceinline__ unsigned short f2bf(float f) {
  uint32_t x; __builtin_memcpy(&x, &f, 4);
  x += 0x7FFFu + ((x >> 16) & 1u);            // RNE (finite values)
  return (unsigned short)(x >> 16);
}

// ---------------- x fp32 -> bf16 ----------------
__global__ __launch_bounds__(256) void k_cast_bf16(const float* __restrict__ in,
    unsigned short* __restrict__ out, int n8) {
  int i = blockIdx.x * 256 + threadIdx.x;
  if (i >= n8) return;
  const float4* p = (const float4*)(in + (size_t)i * 8);
  float4 a = p[0], b = p[1];
  unsigned short r[8] = {f2bf(a.x), f2bf(a.y), f2bf(a.z), f2bf(a.w),
                         f2bf(b.x), f2bf(b.y), f2bf(b.z), f2bf(b.w)};
  *(uint4*)(out + (size_t)i * 8) = *(const uint4*)r;
}

// ---------------- W fp32 [1024][1024] -> bf16 transposed [N][K] ----------------
__global__ __launch_bounds__(256) void k_castT5(
    const float* __restrict__ w0, const float* __restrict__ w1,
    const float* __restrict__ w2, const float* __restrict__ w3,
    const float* __restrict__ w4,
    unsigned short* __restrict__ t0, unsigned short* __restrict__ t1,
    unsigned short* __restrict__ t2, unsigned short* __restrict__ t3,
    unsigned short* __restrict__ t4) {
  __shared__ float tile[32][33];
  int z = blockIdx.z;
  const float* src = z == 0 ? w0 : z == 1 ? w1 : z == 2 ? w2 : z == 3 ? w3 : w4;
  unsigned short* dst = z == 0 ? t0 : z == 1 ? t1 : z == 2 ? t2 : z == 3 ? t3 : t4;
  int c0 = blockIdx.x * 32, r0 = blockIdx.y * 32;
  int tx = threadIdx.x & 31, ty = threadIdx.x >> 5;
  #pragma unroll
  for (int i = 0; i < 4; i++)
    tile[ty + i * 8][tx] = src[(size_t)(r0 + ty + i * 8) * 1024 + c0 + tx];
  __syncthreads();
  #pragma unroll
  for (int i = 0; i < 4; i++)
    dst[(size_t)(c0 + ty + i * 8) * 1024 + r0 + tx] = f2bf(tile[tx][ty + i * 8]);
}

// ---------------- Wa fp32 [1024][16] -> bf16 padded-transposed [128][1024] ----------------
__global__ __launch_bounds__(256) void k_wa_fill(const float* __restrict__ Wa,
    unsigned short* __restrict__ wa_pad) {
  int idx = blockIdx.x * 256 + threadIdx.x;   // 0..131071
  int h = idx >> 10, k2 = idx & 1023;
  wa_pad[idx] = (h < 16) ? f2bf(Wa[k2 * 16 + h]) : (unsigned short)0;
}

// ---------------- inclusive cumsum over s per (b,h) ----------------
__global__ __launch_bounds__(256) void k_cumsum(const float* __restrict__ la,
                                                float* __restrict__ cum) {
  int g = blockIdx.x;
  const float* in = la + (size_t)g * NS;
  float* out = cum + (size_t)g * NS;
  __shared__ float part[256];
  float v[8]; float sum = 0.f;
  int base = threadIdx.x * 8;
  #pragma unroll
  for (int i = 0; i < 8; i++) { v[i] = in[base + i]; sum += v[i]; }
  part[threadIdx.x] = sum;
  __syncthreads();
  for (int off = 1; off < 256; off <<= 1) {
    float add = (threadIdx.x >= off) ? part[threadIdx.x - off] : 0.f;
    __syncthreads();
    part[threadIdx.x] += add;
    __syncthreads();
  }
  float run = (threadIdx.x > 0) ? part[threadIdx.x - 1] : 0.f;
  #pragma unroll
  for (int i = 0; i < 8; i++) { run += v[i]; out[base + i] = run; }
}

// ======================================================================
// k_proj8: fused q|k|v|g projection, 256x256 tile, BK=64, 8 waves,
// counted-vmcnt double-buffered pipeline (T3/T4), pre-swizzled-source T2,
// setprio (T5). Grid exactly 16x16 = 1 block/CU.
// A = xb [4096][1024] bf16 row-major; Wcat [4096][1024] bf16 (W^T concat).
// ======================================================================
__global__ __launch_bounds__(512, 2) void k_proj8(
    const unsigned short* __restrict__ A,
    const unsigned short* __restrict__ Wcat,
    unsigned short* __restrict__ q, unsigned short* __restrict__ k,
    unsigned short* __restrict__ v, unsigned short* __restrict__ g) {
  __shared__ unsigned short Ab[2][256 * 64];   // 64 KB
  __shared__ unsigned short Bb[2][256 * 64];   // 64 KB
  int tid = threadIdx.x;
  // XCD-bijective swizzle (256 % 8 == 0): consecutive logical tiles share an XCD
  int bid = blockIdx.x;                        // 0..255
  int wg = (bid & 7) * 32 + (bid >> 3);
  int bx = wg & 15, by = wg >> 4;
  int row0 = by * 256, col0 = bx * 256;
  int wid = tid >> 6, lane = tid & 63;
  int WR = wid >> 2, WC = wid & 3;             // 2M x 4N wave grid
  int lr = lane & 15, lk = lane >> 4;

  auto stage = [&](int kt, int bi) {
    #pragma unroll
    for (int i = 0; i < 4; i++) {
      int idx = tid + i * 512;                 // chunk 0..2047
      int r = idx >> 3, c = idx & 7;
      int cs = c ^ (r & 7);                    // pre-swizzled source (T2, rule 21)
      const unsigned short* srcA = A + (size_t)(row0 + r) * NM + kt * 64 + cs * 8;
      __builtin_amdgcn_global_load_lds(
          (const __attribute__((address_space(1))) void*)srcA,
          (__attribute__((address_space(3))) void*)((char*)&Ab[bi][0] + (wid * 64 + i * 512) * 16),
          16, 0, 0);
      const unsigned short* srcB = Wcat + (size_t)(col0 + r) * NM + kt * 64 + cs * 8;
      __builtin_amdgcn_global_load_lds(
          (const __attribute__((address_space(1))) void*)srcB,
          (__attribute__((address_space(3))) void*)((char*)&Bb[bi][0] + (wid * 64 + i * 512) * 16),
          16, 0, 0);
    }
  };

  stage(0, 0);
  stage(1, 1);

  f32x4 acc[8][4] = {};
  for (int kt = 0; kt < 16; ++kt) {
    int bi = kt & 1;
    // wait: tile kt fully landed (tile kt+1's 8 loads may remain in flight)
    if (kt < 15) asm volatile("s_waitcnt vmcnt(8)" ::: "memory");
    else         asm volatile("s_waitcnt vmcnt(0)" ::: "memory");
    __builtin_amdgcn_sched_barrier(0);
    __builtin_amdgcn_s_barrier();              // all waves' stages landed

    const char* Ap = (const char*)&Ab[bi][0];
    const char* Bp = (const char*)&Bb[bi][0];
    bf16x8 a0[8], b0[4], a1[8], b1[4];
    #pragma unroll
    for (int m = 0; m < 8; m++) {
      int r = WR * 128 + m * 16 + lr;
      a0[m] = *(const bf16x8*)(Ap + r * 128 + ((lk ^ (r & 7)) * 16));
    }
    #pragma unroll
    for (int n = 0; n < 4; n++) {
      int r = WC * 64 + n * 16 + lr;
      b0[n] = *(const bf16x8*)(Bp + r * 128 + ((lk ^ (r & 7)) * 16));
    }
    // khalf0 MFMA (compiler overlaps khalf1 ds_reads into this)
    #pragma unroll
    for (int m = 0; m < 8; m++)
      #pragma unroll
      for (int n = 0; n < 4; n++)
        acc[m][n] = __builtin_amdgcn_mfma_f32_16x16x32_bf16(a0[m], b0[n], acc[m][n], 0, 0, 0);
    #pragma unroll
    for (int m = 0; m < 8; m++) {
      int r = WR * 128 + m * 16 + lr;
      a1[m] = *(const bf16x8*)(Ap + r * 128 + (((lk + 4) ^ (r & 7)) * 16));
    }
    #pragma unroll
    for (int n = 0; n < 4; n++) {
      int r = WC * 64 + n * 16 + lr;
      b1[n] = *(const bf16x8*)(Bp + r * 128 + (((lk + 4) ^ (r & 7)) * 16));
    }
    asm volatile("s_waitcnt lgkmcnt(0)" ::: "memory");   // all reads of buf bi done
    __builtin_amdgcn_sched_barrier(0);
    __builtin_amdgcn_s_barrier();              // every wave done reading buf bi
    if (kt + 2 < 16) stage(kt + 2, bi);        // overwrite freed buffer
    __builtin_amdgcn_s_setprio(1);
    #pragma unroll
    for (int m = 0; m < 8; m++)
      #pragma unroll
      for (int n = 0; n < 4; n++)
        acc[m][n] = __builtin_amdgcn_mfma_f32_16x16x32_bf16(a1[m], b1[n], acc[m][n], 0, 0, 0);
    __builtin_amdgcn_s_setprio(0);
  }

  // epilogue: zone uniform per block (col0 is 256-aligned within 1024)
  #pragma unroll
  for (int m = 0; m < 8; m++) {
    #pragma unroll
    for (int n = 0; n < 4; n++) {
      int col = col0 + WC * 64 + n * 16 + lr;
      int zone = col >> 10;
      unsigned short* dst = zone == 0 ? q : zone == 1 ? k : zone == 2 ? v : g;
      int cb = col & 1023;
      #pragma unroll
      for (int j = 0; j < 4; j++) {
        int row = row0 + WR * 128 + m * 16 + lk * 4 + j;
        float val = acc[m][n][j];
        if (zone <= 1) val = val / (1.f + expf(-val));        // silu
        else if (zone == 3) val = 1.f / (1.f + expf(-val));   // sigmoid
        dst[(size_t)row * 1024 + cb] = f2bf(val);
      }
    }
  }
}

// ---------------- MFMA bf16 GEMM body (m97 structure + source-swizzled LDS) ----------------
// act: 0 none; 3 = la epilogue: la[(b*16+h)*2048+s] = -softplus(v + ba[h]) for cols<16
__device__ __forceinline__ void gemm_dev(const unsigned short* __restrict__ A,
    const unsigned short* __restrict__ Bt, void* __restrict__ Cp, int N,
    int act, int outbf, int by, int bx, const float* __restrict__ ba) {
  __shared__ unsigned short As[128 * 32];
  __shared__ unsigned short Bs[128 * 32];
  int tid = threadIdx.x;
  int row0 = by * 128, col0 = bx * 128;
  int w = tid >> 6, l = tid & 63;
  int wr = w >> 1, wc = w & 1;
  int lr = l & 15, lk = l >> 4;
  f32x4 acc[4][4] = {};
  for (int k0 = 0; k0 < NM; k0 += 32) {
    __syncthreads();
    #pragma unroll
    for (int i = 0; i < 2; i++) {
      int idx = tid + i * 256;             // 16B-chunk index 0..511
      int r = idx >> 2, c = idx & 3;
      int cs = c ^ ((r >> 1) & 3);         // pre-swizzled source (T2)
      const unsigned short* srcA = A + (size_t)(row0 + r) * NM + k0 + cs * 8;
      const unsigned short* srcB = Bt + (size_t)(col0 + r) * NM + k0 + cs * 8;
      __builtin_amdgcn_global_load_lds(
          (const __attribute__((address_space(1))) void*)srcA,
          (__attribute__((address_space(3))) void*)((char*)As + (w * 64 + i * 256) * 16),
          16, 0, 0);
      __builtin_amdgcn_global_load_lds(
          (const __attribute__((address_space(1))) void*)srcB,
          (__attribute__((address_space(3))) void*)((char*)Bs + (w * 64 + i * 256) * 16),
          16, 0, 0);
    }
    __syncthreads();
    bf16x8 a[4], b[4];
    #pragma unroll
    for (int m = 0; m < 4; m++) {
      int ra = wr * 64 + m * 16 + lr;
      a[m] = *(const bf16x8*)&As[ra * 32 + (lk ^ ((ra >> 1) & 3)) * 8];
    }
    #pragma unroll
    for (int n = 0; n < 4; n++) {
      int rb = wc * 64 + n * 16 + lr;
      b[n] = *(const bf16x8*)&Bs[rb * 32 + (lk ^ ((rb >> 1) & 3)) * 8];
    }
    #pragma unroll
    for (int m = 0; m < 4; m++)
      #pragma unroll
      for (int n = 0; n < 4; n++)
        acc[m][n] = __builtin_amdgcn_mfma_f32_16x16x32_bf16(a[m], b[n], acc[m][n], 0, 0, 0);
  }
  if (act == 3) {                          // alpha-logit epilogue
    if (wc == 0) {
      float bah = ba[lr];
      #pragma unroll
      for (int m = 0; m < 4; m++) {
        #pragma unroll
        for (int j = 0; j < 4; j++) {
          int row = row0 + wr * 64 + m * 16 + lk * 4 + j;   // token index
          float z = acc[m][0][j] + bah;
          float sp = fmaxf(z, 0.f) + log1pf(expf(-fabsf(z)));
          int bb = row >> 11, s = row & 2047;
          ((float*)Cp)[((size_t)(bb * 16 + lr)) * 2048 + s] = -sp;
        }
      }
    }
    return;
  }
  #pragma unroll
  for (int m = 0; m < 4; m++) {
    #pragma unroll
    for (int n = 0; n < 4; n++) {
      #pragma unroll
      for (int j = 0; j < 4; j++) {
        int row = row0 + wr * 64 + m * 16 + lk * 4 + j;
        int col = col0 + wc * 64 + n * 16 + lr;
        float val = acc[m][n][j];
        if (outbf) ((unsigned short*)Cp)[(size_t)row * N + col] = f2bf(val);
        else       ((float*)Cp)[(size_t)row * N + col] = val;
      }
    }
  }
}

__global__ __launch_bounds__(256) void k_la_gemm(const unsigned short* __restrict__ xb,
    const unsigned short* __restrict__ wa_pad, const float* __restrict__ ba,
    float* __restrict__ la) {
  gemm_dev(xb, wa_pad, la, NDI, 3, 1, blockIdx.y, 0, ba);
}

__global__ __launch_bounds__(256) void k_out_gemm(const unsigned short* __restrict__ u,
    const unsigned short* __restrict__ wto, float* __restrict__ out) {
  gemm_dev(u, wto, out, NM, 0, 0, blockIdx.y, blockIdx.x, nullptr);
}

// ---------------- MFMA attention: per (b,h,i-tile of 64 rows) ----------------
__global__ __launch_bounds__(256) void k_attn(const unsigned short* __restrict__ q,
    const unsigned short* __restrict__ kk, const unsigned short* __restrict__ vv,
    const float* __restrict__ cum, float* __restrict__ o) {
  int it = blockIdx.x, h = blockIdx.y, b = blockIdx.z;
  int i0 = it * 64;
  __shared__ unsigned short Qs[64 * 64];
  __shared__ unsigned short Ks[64 * 64];
  __shared__ unsigned short Ps[64 * 64];
  __shared__ unsigned short Vs[64 * 66];
  __shared__ float ci[64], cj[64];
  int tid = threadIdx.x;
  int w = tid >> 6, lane = tid & 63;
  int cl = lane & 15, hi = lane >> 4;
  const size_t hb = (size_t)b * NS * NDI + (size_t)h * ND;
  const float* cumh = cum + (size_t)(b * NH + h) * NS;

  #pragma unroll
  for (int lp = 0; lp < 2; lp++) {
    int idx = tid + lp * 256;
    int r = idx >> 3, cb = (idx & 7) * 16;
    uint4 t = *(const uint4*)(q + hb + (size_t)(i0 + r) * NDI + (cb >> 1));
    *(uint4*)((char*)Qs + r * 128 + (cb ^ ((r & 7) << 4))) = t;
  }
  if (tid < 64) ci[tid] = cumh[i0 + tid];

  int arow = w * 16 + cl;
  int xr = (cl & 7) << 4;
  const char* Qb = (const char*)Qs + arow * 128;
  const char* Pb = (const char*)Ps + arow * 128;
  f32x4 acco[4] = {};

  for (int jt = 0; jt <= it; jt++) {
    int j0 = jt * 64;
    __syncthreads();
    if (tid < 64) cj[tid] = cumh[j0 + tid];
    __syncthreads();
    if (ci[0] - cj[63] < -60.f) continue;
    #pragma unroll
    for (int lp = 0; lp < 2; lp++) {
      int idx = tid + lp * 256;
      int r = idx >> 3, cb = (idx & 7) * 16;
      uint4 t = *(const uint4*)(kk + hb + (size_t)(j0 + r) * NDI + (cb >> 1));
      *(uint4*)((char*)Ks + r * 128 + (cb ^ ((r & 7) << 4))) = t;
      uint4 tv = *(const uint4*)(vv + hb + (size_t)(j0 + r) * NDI + (cb >> 1));
      unsigned int uv[4]; *(uint4*)uv = tv;
      unsigned int* vd = (unsigned int*)(Vs + r * 66 + (cb >> 1));
      vd[0] = uv[0]; vd[1] = uv[1]; vd[2] = uv[2]; vd[3] = uv[3];
    }
    __syncthreads();
    bf16x8 a0 = *(const bf16x8*)(Qb + ((hi * 16) ^ xr));
    bf16x8 a1 = *(const bf16x8*)(Qb + ((64 + hi * 16) ^ xr));
    f32x4 accs[4] = {};
    #pragma unroll
    for (int jtile = 0; jtile < 4; jtile++) {
      const char* Kb = (const char*)Ks + (jtile * 16 + cl) * 128;
      bf16x8 b0 = *(const bf16x8*)(Kb + ((hi * 16) ^ xr));
      bf16x8 b1 = *(const bf16x8*)(Kb + ((64 + hi * 16) ^ xr));
      accs[jtile] = __builtin_amdgcn_mfma_f32_16x16x32_bf16(a0, b0, accs[jtile], 0, 0, 0);
      accs[jtile] = __builtin_amdgcn_mfma_f32_16x16x32_bf16(a1, b1, accs[jtile], 0, 0, 0);
    }
    #pragma unroll
    for (int jtile = 0; jtile < 4; jtile++) {
      #pragma unroll
      for (int reg = 0; reg < 4; reg++) {
        int irl = w * 16 + hi * 4 + reg;
        int jl = jtile * 16 + cl;
        float dec = ((j0 + jl) <= (i0 + irl)) ? __expf(ci[irl] - cj[jl]) : 0.f;
        float pv = accs[jtile][reg] * dec;
        *(unsigned short*)((char*)Ps + irl * 128 + ((2 * jl) ^ ((irl & 7) << 4))) = f2bf(pv);
      }
    }
    __syncthreads();
    #pragma unroll
    for (int kk2 = 0; kk2 < 2; kk2++) {
      bf16x8 pa = *(const bf16x8*)(Pb + ((kk2 * 64 + hi * 16) ^ xr));
      #pragma unroll
      for (int dt = 0; dt < 4; dt++) {
        bf16x8 vb;
        #pragma unroll
        for (int e = 0; e < 8; e++)
          vb[e] = (short)Vs[(kk2 * 32 + hi * 8 + e) * 66 + dt * 16 + cl];
        acco[dt] = __builtin_amdgcn_mfma_f32_16x16x32_bf16(pa, vb, acco[dt], 0, 0, 0);
      }
    }
  }
  #pragma unroll
  for (int dt = 0; dt < 4; dt++) {
    #pragma unroll
    for (int reg = 0; reg < 4; reg++) {
      int row = i0 + w * 16 + hi * 4 + reg;
      o[hb + (size_t)row * NDI + dt * 16 + cl] = acco[dt][reg];
    }
  }
}

// ---------------- groupnorm stats ----------------
__global__ __launch_bounds__(256) void k_gnpart(const float* __restrict__ o,
    float* __restrict__ psum, float* __restrict__ psq) {
  int chunk = blockIdx.x;
  int g = blockIdx.y;
  int b = g >> 4, h = g & 15;
  int s0 = chunk * 256;
  int d = threadIdx.x & 63;
  int si = threadIdx.x >> 6;
  const size_t base = (size_t)b * NS * NDI + (size_t)h * ND + d;
  float sum = 0.f, sq = 0.f;
  for (int s = s0 + si; s < s0 + 256; s += 4) {
    float t = o[base + (size_t)s * NDI];
    sum += t; sq += t * t;
  }
  __shared__ float ls[256], lq[256];
  ls[threadIdx.x] = sum; lq[threadIdx.x] = sq;
  __syncthreads();
  for (int off = 128; off > 0; off >>= 1) {
    if (threadIdx.x < off) {
      ls[threadIdx.x] += ls[threadIdx.x + off];
      lq[threadIdx.x] += lq[threadIdx.x + off];
    }
    __syncthreads();
  }
  if (threadIdx.x == 0) { psum[g * 8 + chunk] = ls[0]; psq[g * 8 + chunk] = lq[0]; }
}

__global__ void k_gnfinal(const float* __restrict__ psum, const float* __restrict__ psq,
                          float* __restrict__ stats) {
  int g = threadIdx.x;
  if (g < 32) {
    float sum = 0.f, sq = 0.f;
    for (int c = 0; c < 8; c++) { sum += psum[g * 8 + c]; sq += psq[g * 8 + c]; }
    float n = (float)(NS * ND);
    float mean = sum / n;
    float var = sq / n - mean * mean;
    stats[g * 2] = mean;
    stats[g * 2 + 1] = rsqrtf(var + 1e-5f);
  }
}

// ---------------- u = (groupnorm(o)*w+b)*gate, bf16 out ----------------
__global__ __launch_bounds__(256) void k_gate(const float* __restrict__ o,
    const unsigned short* __restrict__ gsig, const float* __restrict__ stats,
    const float* __restrict__ gnw, const float* __restrict__ gnb,
    unsigned short* __restrict__ u) {
  int idx4 = blockIdx.x * 256 + threadIdx.x;
  size_t base = (size_t)idx4 * 4;
  int c = (int)(base & (NDI - 1));
  int row = (int)(base >> 10);
  int b = row >> 11;
  int h = c >> 6;
  int g = b * NH + h;
  float mean = stats[g * 2], rstd = stats[g * 2 + 1];
  float4 ov = *(const float4*)(o + base);
  ushort4 gv = *(const ushort4*)(gsig + base);
  float4 w4 = *(const float4*)(gnw + c);
  float4 b4 = *(const float4*)(gnb + c);
  unsigned short r[4];
  r[0] = f2bf(((ov.x - mean) * rstd * w4.x + b4.x) * bf2f(gv.x));
  r[1] = f2bf(((ov.y - mean) * rstd * w4.y + b4.y) * bf2f(gv.y));
  r[2] = f2bf(((ov.z - mean) * rstd * w4.z + b4.z) * bf2f(gv.z));
  r[3] = f2bf(((ov.w - mean) * rstd * w4.w + b4.w) * bf2f(gv.w));
  *(ushort4*)(u + base) = *(const ushort4*)r;
}

extern "C" void kernel_launch(void* const* d_in, const int* in_sizes, int n_in,
                              void* d_out, int out_size, void* d_ws, size_t ws_size,
                              hipStream_t stream) {
  const float* x   = (const float*)d_in[0];
  const float* Wq  = (const float*)d_in[1];
  const float* Wk  = (const float*)d_in[2];
  const float* Wv  = (const float*)d_in[3];
  const float* Wg  = (const float*)d_in[4];
  const float* Wa  = (const float*)d_in[5];
  const float* ba  = (const float*)d_in[6];
  const float* Wo  = (const float*)d_in[7];
  const float* gnw = (const float*)d_in[8];
  const float* gnb = (const float*)d_in[9];
  float* out = (float*)d_out;

  const size_t NTOK = (size_t)NB * NS;        // 4096
  char* p = (char*)d_ws;
  float* la  = (float*)p;                 p += (size_t)NB * NH * NS * 4;
  float* cum = (float*)p;                 p += (size_t)NB * NH * NS * 4;
  float* psum = (float*)p;                p += 256 * 4;
  float* psq  = (float*)p;                p += 256 * 4;
  float* stats = (float*)p;               p += 64 * 4;
  p = (char*)(((uintptr_t)p + 255) & ~(uintptr_t)255);
  unsigned short* xb   = (unsigned short*)p; p += NTOK * NM * 2;        // 8 MB
  unsigned short* Wcat = (unsigned short*)p; p += (size_t)4 * NM * NDI * 2; // 8 MB
  unsigned short* wto  = (unsigned short*)p; p += (size_t)NDI * NM * 2;
  unsigned short* wa_pad = (unsigned short*)p; p += (size_t)128 * NM * 2;
  unsigned short* q  = (unsigned short*)p;  p += NTOK * NDI * 2;
  unsigned short* k  = (unsigned short*)p;  p += NTOK * NDI * 2;
  unsigned short* v  = (unsigned short*)p;  p += NTOK * NDI * 2;
  unsigned short* g  = (unsigned short*)p;  p += NTOK * NDI * 2;
  unsigned short* u  = (unsigned short*)p;  p += NTOK * NDI * 2;
  float* o = (float*)p;                     p += NTOK * NDI * 4;

  unsigned short* wtq = Wcat;
  unsigned short* wtk = Wcat + (size_t)NM * NDI;
  unsigned short* wtv = Wcat + (size_t)2 * NM * NDI;
  unsigned short* wtg = Wcat + (size_t)3 * NM * NDI;

  k_cast_bf16<<<dim3((int)(NTOK * NM / 8 / 256)), 256, 0, stream>>>(x, xb, (int)(NTOK * NM / 8));
  k_castT5   <<<dim3(32, 32, 5), 256, 0, stream>>>(Wq, Wk, Wv, Wg, Wo, wtq, wtk, wtv, wtg, wto);
  k_wa_fill  <<<dim3(512), 256, 0, stream>>>(Wa, wa_pad);
  k_la_gemm  <<<dim3(1, 32), 256, 0, stream>>>(xb, wa_pad, ba, la);
  k_cumsum   <<<dim3(NB * NH), 256, 0, stream>>>(la, cum);
  k_proj8    <<<dim3(256), 512, 0, stream>>>(xb, Wcat, q, k, v, g);
  k_attn     <<<dim3(32, NH, NB), 256, 0, stream>>>(q, k, v, cum, o);
  k_gnpart   <<<dim3(8, 32), 256, 0, stream>>>(o, psum, psq);
  k_gnfinal  <<<1, 64, 0, stream>>>(psum, psq, stats);
  k_gate     <<<dim3(4096), 256, 0, stream>>>(o, g, stats, gnw, gnb, u);
  k_out_gemm <<<dim3(8, 32), 256, 0, stream>>>(u, wto, out);
}